// Round 1
// baseline (171.574 us; speedup 1.0000x reference)
//
#include <hip/hip_runtime.h>

// Weighted3DTransformNormLoss — MI355X (gfx950)
// loss = 0.5/size * sum_{b,k,h,w} mask * ||(R-I)p + (t - tf)||^2 / (0.5||tf||^2 + eps)

constexpr int BATCH = 32;
constexpr int KK    = 8;
constexpr int H     = 240;
constexpr int W     = 320;
constexpr int HW    = H * W;                 // 76800
constexpr float EPS = 0.001f;
constexpr float SCALE = 0.5f / (float)(BATCH * 3 * HW);  // 0.5 / inputpts.size

__global__ void zero_out_kernel(float* out) { *out = 0.0f; }

__global__ __launch_bounds__(256) void w3d_loss_kernel(
    const float* __restrict__ pts,     // [B,3,H,W]
    const float* __restrict__ masks,   // [B,K,H,W]
    const float* __restrict__ tfms,    // [B,K,3,4]
    const float* __restrict__ flows,   // [B,3,H,W]
    float* __restrict__ out)
{
    __shared__ float sT[KK * 12];   // per-k: M=R-I (rows interleaved with t): [m0 m1 m2 t]x3
    __shared__ float sWave[4];

    const int b   = blockIdx.y;
    const int tid = threadIdx.x;

    // Stage transforms for this batch; subtract identity from R on the fly.
    if (tid < KK * 12) {
        float v = tfms[b * KK * 12 + tid];
        int j  = tid % 12;
        int i  = j >> 2;        // row
        int jj = j & 3;         // col (3 == translation)
        if (jj < 3 && i == jj) v -= 1.0f;
        sT[tid] = v;
    }
    __syncthreads();

    const int base = (blockIdx.x * 256 + tid) * 4;   // 4 pixels per thread
    const float* pb = pts   + (size_t)b * 3  * HW;
    const float* fb = flows + (size_t)b * 3  * HW;
    const float* mb = masks + (size_t)b * KK * HW;

    const float4 p0 = *(const float4*)(pb + 0 * HW + base);
    const float4 p1 = *(const float4*)(pb + 1 * HW + base);
    const float4 p2 = *(const float4*)(pb + 2 * HW + base);
    const float4 f0 = *(const float4*)(fb + 0 * HW + base);
    const float4 f1 = *(const float4*)(fb + 1 * HW + base);
    const float4 f2 = *(const float4*)(fb + 2 * HW + base);

    const float P0[4] = {p0.x, p0.y, p0.z, p0.w};
    const float P1[4] = {p1.x, p1.y, p1.z, p1.w};
    const float P2[4] = {p2.x, p2.y, p2.z, p2.w};
    const float F0[4] = {f0.x, f0.y, f0.z, f0.w};
    const float F1[4] = {f1.x, f1.y, f1.z, f1.w};
    const float F2[4] = {f2.x, f2.y, f2.z, f2.w};

    float accp[4] = {0.f, 0.f, 0.f, 0.f};

    #pragma unroll
    for (int k = 0; k < KK; ++k) {
        const float m00 = sT[k*12+0], m01 = sT[k*12+1], m02 = sT[k*12+2],  t0 = sT[k*12+3];
        const float m10 = sT[k*12+4], m11 = sT[k*12+5], m12 = sT[k*12+6],  t1 = sT[k*12+7];
        const float m20 = sT[k*12+8], m21 = sT[k*12+9], m22 = sT[k*12+10], t2 = sT[k*12+11];

        const float4 mk = *(const float4*)(mb + k * HW + base);
        const float MK[4] = {mk.x, mk.y, mk.z, mk.w};

        #pragma unroll
        for (int e = 0; e < 4; ++e) {
            float d0 = fmaf(m00, P0[e], fmaf(m01, P1[e], fmaf(m02, P2[e], t0 - F0[e])));
            float d1 = fmaf(m10, P0[e], fmaf(m11, P1[e], fmaf(m12, P2[e], t1 - F1[e])));
            float d2 = fmaf(m20, P0[e], fmaf(m21, P1[e], fmaf(m22, P2[e], t2 - F2[e])));
            float sq = fmaf(d0, d0, fmaf(d1, d1, d2 * d2));
            accp[e]  = fmaf(MK[e], sq, accp[e]);
        }
    }

    float acc = 0.f;
    #pragma unroll
    for (int e = 0; e < 4; ++e) {
        // sigma = 0.5*||tf||^2 + eps   (divide once per pixel, factored out of k-loop)
        float sig = fmaf(0.5f * F0[e], F0[e],
                    fmaf(0.5f * F1[e], F1[e],
                    fmaf(0.5f * F2[e], F2[e], EPS)));
        acc += accp[e] / sig;
    }

    // Wave (64-lane) reduction, then cross-wave via LDS, one atomic per block.
    #pragma unroll
    for (int off = 32; off > 0; off >>= 1) acc += __shfl_down(acc, off);
    if ((tid & 63) == 0) sWave[tid >> 6] = acc;
    __syncthreads();
    if (tid == 0) {
        float s = (sWave[0] + sWave[1]) + (sWave[2] + sWave[3]);
        atomicAdd(out, s * SCALE);
    }
}

extern "C" void kernel_launch(void* const* d_in, const int* in_sizes, int n_in,
                              void* d_out, int out_size, void* d_ws, size_t ws_size,
                              hipStream_t stream) {
    const float* pts   = (const float*)d_in[0];
    const float* masks = (const float*)d_in[1];
    const float* tfms  = (const float*)d_in[2];
    const float* flows = (const float*)d_in[3];
    float* out = (float*)d_out;

    zero_out_kernel<<<1, 1, 0, stream>>>(out);

    dim3 grid(HW / (256 * 4), BATCH);   // (75, 32) = 2400 blocks
    w3d_loss_kernel<<<grid, 256, 0, stream>>>(pts, masks, tfms, flows, out);
}

// Round 2
// 171.321 us; speedup vs baseline: 1.0015x; 1.0015x over previous
//
#include <hip/hip_runtime.h>

// Weighted3DTransformNormLoss — MI355X (gfx950)
// loss = 0.5/size * sum_{b,k,h,w} mask * ||(R-I)p + (t - tf)||^2 / (0.5||tf||^2 + eps)
//
// R2: maximize MLP — issue all 14 float4 loads (6 p/f + 8 masks) before any
// compute wait; zero d_out via hipMemsetAsync instead of a 1-thread kernel.

constexpr int BATCH = 32;
constexpr int KK    = 8;
constexpr int H     = 240;
constexpr int W     = 320;
constexpr int HW    = H * W;                 // 76800
constexpr float EPS = 0.001f;
constexpr float SCALE = 0.5f / (float)(BATCH * 3 * HW);  // 0.5 / inputpts.size

__global__ __launch_bounds__(256, 4) void w3d_loss_kernel(
    const float* __restrict__ pts,     // [B,3,H,W]
    const float* __restrict__ masks,   // [B,K,H,W]
    const float* __restrict__ tfms,    // [B,K,3,4]
    const float* __restrict__ flows,   // [B,3,H,W]
    float* __restrict__ out)
{
    __shared__ float sT[KK * 12];   // per-k: rows of M=R-I interleaved with t
    __shared__ float sWave[4];

    const int b   = blockIdx.y;
    const int tid = threadIdx.x;

    if (tid < KK * 12) {
        float v = tfms[b * KK * 12 + tid];
        int j  = tid % 12;
        int i  = j >> 2;        // row
        int jj = j & 3;         // col (3 == translation)
        if (jj < 3 && i == jj) v -= 1.0f;
        sT[tid] = v;
    }
    __syncthreads();

    const int base = (blockIdx.x * 256 + tid) * 4;   // 4 pixels per thread
    const float* pb = pts   + (size_t)b * 3  * HW;
    const float* fb = flows + (size_t)b * 3  * HW;
    const float* mb = masks + (size_t)b * KK * HW;

    // ---- issue ALL loads up front (14 float4 = 224 B/thread in flight) ----
    const float4 p0 = *(const float4*)(pb + 0 * HW + base);
    const float4 p1 = *(const float4*)(pb + 1 * HW + base);
    const float4 p2 = *(const float4*)(pb + 2 * HW + base);
    const float4 f0 = *(const float4*)(fb + 0 * HW + base);
    const float4 f1 = *(const float4*)(fb + 1 * HW + base);
    const float4 f2 = *(const float4*)(fb + 2 * HW + base);

    float4 mk[KK];
    #pragma unroll
    for (int k = 0; k < KK; ++k)
        mk[k] = *(const float4*)(mb + k * HW + base);

    const float P0[4] = {p0.x, p0.y, p0.z, p0.w};
    const float P1[4] = {p1.x, p1.y, p1.z, p1.w};
    const float P2[4] = {p2.x, p2.y, p2.z, p2.w};
    const float F0[4] = {f0.x, f0.y, f0.z, f0.w};
    const float F1[4] = {f1.x, f1.y, f1.z, f1.w};
    const float F2[4] = {f2.x, f2.y, f2.z, f2.w};

    float accp[4] = {0.f, 0.f, 0.f, 0.f};

    #pragma unroll
    for (int k = 0; k < KK; ++k) {
        const float m00 = sT[k*12+0], m01 = sT[k*12+1], m02 = sT[k*12+2],  t0 = sT[k*12+3];
        const float m10 = sT[k*12+4], m11 = sT[k*12+5], m12 = sT[k*12+6],  t1 = sT[k*12+7];
        const float m20 = sT[k*12+8], m21 = sT[k*12+9], m22 = sT[k*12+10], t2 = sT[k*12+11];
        const float MK[4] = {mk[k].x, mk[k].y, mk[k].z, mk[k].w};

        #pragma unroll
        for (int e = 0; e < 4; ++e) {
            float d0 = fmaf(m00, P0[e], fmaf(m01, P1[e], fmaf(m02, P2[e], t0 - F0[e])));
            float d1 = fmaf(m10, P0[e], fmaf(m11, P1[e], fmaf(m12, P2[e], t1 - F1[e])));
            float d2 = fmaf(m20, P0[e], fmaf(m21, P1[e], fmaf(m22, P2[e], t2 - F2[e])));
            float sq = fmaf(d0, d0, fmaf(d1, d1, d2 * d2));
            accp[e]  = fmaf(MK[e], sq, accp[e]);
        }
    }

    float acc = 0.f;
    #pragma unroll
    for (int e = 0; e < 4; ++e) {
        float sig = fmaf(0.5f * F0[e], F0[e],
                    fmaf(0.5f * F1[e], F1[e],
                    fmaf(0.5f * F2[e], F2[e], EPS)));
        acc += accp[e] / sig;
    }

    #pragma unroll
    for (int off = 32; off > 0; off >>= 1) acc += __shfl_down(acc, off);
    if ((tid & 63) == 0) sWave[tid >> 6] = acc;
    __syncthreads();
    if (tid == 0) {
        float s = (sWave[0] + sWave[1]) + (sWave[2] + sWave[3]);
        atomicAdd(out, s * SCALE);
    }
}

extern "C" void kernel_launch(void* const* d_in, const int* in_sizes, int n_in,
                              void* d_out, int out_size, void* d_ws, size_t ws_size,
                              hipStream_t stream) {
    const float* pts   = (const float*)d_in[0];
    const float* masks = (const float*)d_in[1];
    const float* tfms  = (const float*)d_in[2];
    const float* flows = (const float*)d_in[3];
    float* out = (float*)d_out;

    hipMemsetAsync(out, 0, sizeof(float), stream);

    dim3 grid(HW / (256 * 4), BATCH);   // (75, 32) = 2400 blocks
    w3d_loss_kernel<<<grid, 256, 0, stream>>>(pts, masks, tfms, flows, out);
}

// Round 3
// 166.122 us; speedup vs baseline: 1.0328x; 1.0313x over previous
//
#include <hip/hip_runtime.h>

// Weighted3DTransformNormLoss — MI355X (gfx950)
// loss = 0.5/size * sum_{b,k,h,w} mask * ||(R-I)p + (t - tf)||^2 / (0.5||tf||^2 + eps)
//
// R3: remove the same-address atomicAdd drain (2400 serialized far-atomics
// ~= the whole 56us). Blocks store partials to d_ws; a 1-block kernel reduces.

constexpr int BATCH = 32;
constexpr int KK    = 8;
constexpr int H     = 240;
constexpr int W     = 320;
constexpr int HW    = H * W;                 // 76800
constexpr float EPS = 0.001f;
constexpr float SCALE = 0.5f / (float)(BATCH * 3 * HW);  // 0.5 / inputpts.size

constexpr int PIX_PER_THREAD = 4;
constexpr int BLOCKS_X = HW / (256 * PIX_PER_THREAD);    // 75
constexpr int NPARTIAL = BLOCKS_X * BATCH;               // 2400

__global__ __launch_bounds__(256, 4) void w3d_loss_kernel(
    const float* __restrict__ pts,     // [B,3,H,W]
    const float* __restrict__ masks,   // [B,K,H,W]
    const float* __restrict__ tfms,    // [B,K,3,4]
    const float* __restrict__ flows,   // [B,3,H,W]
    float* __restrict__ partials)      // [NPARTIAL]
{
    __shared__ float sT[KK * 12];   // per-k: rows of M=R-I interleaved with t
    __shared__ float sWave[4];

    const int b   = blockIdx.y;
    const int tid = threadIdx.x;

    if (tid < KK * 12) {
        float v = tfms[b * KK * 12 + tid];
        int j  = tid % 12;
        int i  = j >> 2;        // row
        int jj = j & 3;         // col (3 == translation)
        if (jj < 3 && i == jj) v -= 1.0f;
        sT[tid] = v;
    }
    __syncthreads();

    const int base = (blockIdx.x * 256 + tid) * PIX_PER_THREAD;
    const float* pb = pts   + (size_t)b * 3  * HW;
    const float* fb = flows + (size_t)b * 3  * HW;
    const float* mb = masks + (size_t)b * KK * HW;

    const float4 p0 = *(const float4*)(pb + 0 * HW + base);
    const float4 p1 = *(const float4*)(pb + 1 * HW + base);
    const float4 p2 = *(const float4*)(pb + 2 * HW + base);
    const float4 f0 = *(const float4*)(fb + 0 * HW + base);
    const float4 f1 = *(const float4*)(fb + 1 * HW + base);
    const float4 f2 = *(const float4*)(fb + 2 * HW + base);

    float4 mk[KK];
    #pragma unroll
    for (int k = 0; k < KK; ++k)
        mk[k] = *(const float4*)(mb + k * HW + base);

    const float P0[4] = {p0.x, p0.y, p0.z, p0.w};
    const float P1[4] = {p1.x, p1.y, p1.z, p1.w};
    const float P2[4] = {p2.x, p2.y, p2.z, p2.w};
    const float F0[4] = {f0.x, f0.y, f0.z, f0.w};
    const float F1[4] = {f1.x, f1.y, f1.z, f1.w};
    const float F2[4] = {f2.x, f2.y, f2.z, f2.w};

    float accp[4] = {0.f, 0.f, 0.f, 0.f};

    #pragma unroll
    for (int k = 0; k < KK; ++k) {
        const float m00 = sT[k*12+0], m01 = sT[k*12+1], m02 = sT[k*12+2],  t0 = sT[k*12+3];
        const float m10 = sT[k*12+4], m11 = sT[k*12+5], m12 = sT[k*12+6],  t1 = sT[k*12+7];
        const float m20 = sT[k*12+8], m21 = sT[k*12+9], m22 = sT[k*12+10], t2 = sT[k*12+11];
        const float MK[4] = {mk[k].x, mk[k].y, mk[k].z, mk[k].w};

        #pragma unroll
        for (int e = 0; e < 4; ++e) {
            float d0 = fmaf(m00, P0[e], fmaf(m01, P1[e], fmaf(m02, P2[e], t0 - F0[e])));
            float d1 = fmaf(m10, P0[e], fmaf(m11, P1[e], fmaf(m12, P2[e], t1 - F1[e])));
            float d2 = fmaf(m20, P0[e], fmaf(m21, P1[e], fmaf(m22, P2[e], t2 - F2[e])));
            float sq = fmaf(d0, d0, fmaf(d1, d1, d2 * d2));
            accp[e]  = fmaf(MK[e], sq, accp[e]);
        }
    }

    float acc = 0.f;
    #pragma unroll
    for (int e = 0; e < 4; ++e) {
        float sig = fmaf(0.5f * F0[e], F0[e],
                    fmaf(0.5f * F1[e], F1[e],
                    fmaf(0.5f * F2[e], F2[e], EPS)));
        acc += accp[e] / sig;
    }

    #pragma unroll
    for (int off = 32; off > 0; off >>= 1) acc += __shfl_down(acc, off);
    if ((tid & 63) == 0) sWave[tid >> 6] = acc;
    __syncthreads();
    if (tid == 0) {
        float s = (sWave[0] + sWave[1]) + (sWave[2] + sWave[3]);
        partials[blockIdx.y * gridDim.x + blockIdx.x] = s;   // plain store, no atomic
    }
}

__global__ __launch_bounds__(256) void reduce_kernel(
    const float* __restrict__ partials, float* __restrict__ out)
{
    __shared__ float sWave[4];
    const int tid = threadIdx.x;

    float acc = 0.f;
    for (int i = tid; i < NPARTIAL; i += 256) acc += partials[i];

    #pragma unroll
    for (int off = 32; off > 0; off >>= 1) acc += __shfl_down(acc, off);
    if ((tid & 63) == 0) sWave[tid >> 6] = acc;
    __syncthreads();
    if (tid == 0) {
        float s = (sWave[0] + sWave[1]) + (sWave[2] + sWave[3]);
        out[0] = s * SCALE;
    }
}

extern "C" void kernel_launch(void* const* d_in, const int* in_sizes, int n_in,
                              void* d_out, int out_size, void* d_ws, size_t ws_size,
                              hipStream_t stream) {
    const float* pts   = (const float*)d_in[0];
    const float* masks = (const float*)d_in[1];
    const float* tfms  = (const float*)d_in[2];
    const float* flows = (const float*)d_in[3];
    float* out      = (float*)d_out;
    float* partials = (float*)d_ws;    // NPARTIAL floats (9.6 KB) of scratch

    dim3 grid(BLOCKS_X, BATCH);        // (75, 32) = 2400 blocks
    w3d_loss_kernel<<<grid, 256, 0, stream>>>(pts, masks, tfms, flows, partials);
    reduce_kernel<<<1, 256, 0, stream>>>(partials, out);
}